// Round 4
// baseline (55.079 us; speedup 1.0000x reference)
//
#include <hip/hip_runtime.h>

// x (64, 1024, 1024) fp32.
// out[0..63]   = trace(x[b])        = sum_i x[b,i,i]
// out[64..127] = trace(x[b] @ x[b]) = sum_{i,j} x[b,i,j]*x[b,j,i]
//
// R3: 128x128 super-tile pairs; every global read is a 512B contiguous
// wave-segment; B staged in two 32KB LDS phases (interleaved row-pairs);
// A held in 32 VGPRs; HBM traffic exactly 256 MiB. 81.5 -> 49.6 us.
// R4: single change — non-temporal loads (data is touched exactly once;
// skip L1/L2 allocation on the streaming reads).

#define N 1024
#define NB 64
#define BT 128
#define NT2 (N / BT)                   // 8
#define NPAIR2 (NT2 * (NT2 + 1) / 2)   // 36

typedef float f32x4 __attribute__((ext_vector_type(4)));

__global__ void zero_out_kernel(float* out) {
    int t = threadIdx.x;
    if (t < 2 * NB) out[t] = 0.0f;
}

__device__ __forceinline__ f32x4 ldnt(const float* p) {
    return __builtin_nontemporal_load(reinterpret_cast<const f32x4*>(p));
}

__global__ __launch_bounds__(512) void trace_pair_kernel(const float* __restrict__ x,
                                                         float* __restrict__ out) {
    __shared__ float bt[64][129];   // 32.25 KB; pad 129: transposed reads 2-way (free)
    __shared__ float red[16];

    const int blk = blockIdx.x;
    const int b   = blk / NPAIR2;
    int p = blk % NPAIR2;
    int bi = 0;
    while (p >= NT2 - bi) { p -= NT2 - bi; ++bi; }
    const int bj = bi + p;
    const bool diag = (bi == bj);

    const float* xb = x + (size_t)b * N * N;
    const int t  = threadIdx.x;
    const int g  = t & 31;    // float4 col within super-tile (0..31)
    const int rb = t >> 5;    // row base (0..15)

    const float* Arow0 = xb + (size_t)(BT * bi) * N + BT * bj + 4 * g;
    const float* Brow0 = xb + (size_t)(BT * bj) * N + BT * bi + 4 * g;

    // A super-tile: 8 rows/thread, 512B contiguous per wave-row.
    f32x4 av[8];
    #pragma unroll
    for (int rr = 0; rr < 8; ++rr) {
        av[rr] = ldnt(Arow0 + (size_t)(rb + 16 * rr) * N);
    }

    // Phase-0 B rows (off-diag only): loader row lr covers c = 4*(lr>>1)+(lr&1).
    f32x4 bv[4];
    if (!diag) {
        #pragma unroll
        for (int q = 0; q < 4; ++q) {
            const int lr = rb + 16 * q;
            const int c  = 4 * (lr >> 1) + (lr & 1);
            bv[q] = ldnt(Brow0 + (size_t)c * N);
        }
    }

    // Stage phase 0 (slot for row c is 2*(c>>2)+(c&1) == lr by construction).
    if (diag) {
        if (((rb >> 1) & 1) == 0) {
            #pragma unroll
            for (int rr = 0; rr < 8; ++rr) {
                const int r = rb + 16 * rr;
                const int slot = 2 * (r >> 2) + (r & 1);
                bt[slot][4 * g + 0] = av[rr].x;
                bt[slot][4 * g + 1] = av[rr].y;
                bt[slot][4 * g + 2] = av[rr].z;
                bt[slot][4 * g + 3] = av[rr].w;
            }
        }
    } else {
        #pragma unroll
        for (int q = 0; q < 4; ++q) {
            const int lr = rb + 16 * q;
            bt[lr][4 * g + 0] = bv[q].x;
            bt[lr][4 * g + 1] = bv[q].y;
            bt[lr][4 * g + 2] = bv[q].z;
            bt[lr][4 * g + 3] = bv[q].w;
        }
    }
    __syncthreads();

    // Prefetch phase-1 B rows (c = 4*(lr>>1)+2+(lr&1)) under phase-0 compute.
    if (!diag) {
        #pragma unroll
        for (int q = 0; q < 4; ++q) {
            const int lr = rb + 16 * q;
            const int c  = 4 * (lr >> 1) + 2 + (lr & 1);
            bv[q] = ldnt(Brow0 + (size_t)c * N);
        }
    }

    float s  = 0.0f;
    float tr = 0.0f;

    // Compute phase 0: c = 4g+j, j in {0,1} -> av components x,y.
    #pragma unroll
    for (int rr = 0; rr < 8; ++rr) {
        const int r = rb + 16 * rr;
        s += av[rr].x * bt[2 * g + 0][r];
        s += av[rr].y * bt[2 * g + 1][r];
    }

    // Trace from registers (diag blocks own A==B; element (r,r) is held by
    // the thread with g == r>>2, rb == r&15; component = rb&3).
    if (diag) {
        const int cc = rb & 3;
        #pragma unroll
        for (int rr = 0; rr < 8; ++rr) {
            const int r = rb + 16 * rr;
            if ((r >> 2) == g) {
                tr += (cc == 0) ? av[rr].x : (cc == 1) ? av[rr].y
                    : (cc == 2) ? av[rr].z : av[rr].w;
            }
        }
    }

    __syncthreads();   // drain phase-0 reads before overwrite

    // Stage phase 1.
    if (diag) {
        if (((rb >> 1) & 1) == 1) {
            #pragma unroll
            for (int rr = 0; rr < 8; ++rr) {
                const int r = rb + 16 * rr;
                const int slot = 2 * (r >> 2) + (r & 1);
                bt[slot][4 * g + 0] = av[rr].x;
                bt[slot][4 * g + 1] = av[rr].y;
                bt[slot][4 * g + 2] = av[rr].z;
                bt[slot][4 * g + 3] = av[rr].w;
            }
        }
    } else {
        #pragma unroll
        for (int q = 0; q < 4; ++q) {
            const int lr = rb + 16 * q;
            bt[lr][4 * g + 0] = bv[q].x;
            bt[lr][4 * g + 1] = bv[q].y;
            bt[lr][4 * g + 2] = bv[q].z;
            bt[lr][4 * g + 3] = bv[q].w;
        }
    }
    __syncthreads();

    // Compute phase 1: c = 4g+2+j -> av components z,w. Same LDS slots.
    #pragma unroll
    for (int rr = 0; rr < 8; ++rr) {
        const int r = rb + 16 * rr;
        s += av[rr].z * bt[2 * g + 0][r];
        s += av[rr].w * bt[2 * g + 1][r];
    }

    if (!diag) s *= 2.0f;   // (BI,BJ) and (BJ,BI) contribute equally

    // Block reduction: wave64 shuffle, then cross-wave via LDS (8 waves).
    #pragma unroll
    for (int off = 32; off > 0; off >>= 1) {
        s  += __shfl_down(s,  off, 64);
        tr += __shfl_down(tr, off, 64);
    }
    const int wave = t >> 6;
    const int lane = t & 63;
    if (lane == 0) { red[wave] = s; red[8 + wave] = tr; }
    __syncthreads();
    if (t == 0) {
        float st = 0.0f, trt = 0.0f;
        #pragma unroll
        for (int w = 0; w < 8; ++w) { st += red[w]; trt += red[8 + w]; }
        atomicAdd(out + NB + b, st);
        if (diag) atomicAdd(out + b, trt);
    }
}

extern "C" void kernel_launch(void* const* d_in, const int* in_sizes, int n_in,
                              void* d_out, int out_size, void* d_ws, size_t ws_size,
                              hipStream_t stream) {
    (void)in_sizes; (void)n_in; (void)d_ws; (void)ws_size; (void)out_size;
    const float* x = (const float*)d_in[0];
    float* out = (float*)d_out;

    zero_out_kernel<<<1, 128, 0, stream>>>(out);
    trace_pair_kernel<<<NB * NPAIR2, 512, 0, stream>>>(x, out);
}

// Round 5
// 50.953 us; speedup vs baseline: 1.0810x; 1.0810x over previous
//
#include <hip/hip_runtime.h>

// x (64, 1024, 1024) fp32.
// out[0..63]   = trace(x[b])        = sum_i x[b,i,i]
// out[64..127] = trace(x[b] @ x[b]) = sum_{i,j} x[b,i,j]*x[b,j,i]
//
// R3: 128x128 super-tile pairs; every global read is a 512B contiguous
// wave-segment; B staged in two 32KB LDS phases (interleaved row-pairs);
// A held in 32 VGPRs; HBM traffic exactly 256 MiB. 81.5 -> 49.6 us.
// R4: non-temporal loads — REGRESSED (55.1 us): input fits the 256MiB L3 and
// stays partially resident across replays; nt bypasses that. Reverted.
// R5: plain loads (R3 path) + replace the zero_out kernel dispatch with a
// hipMemsetAsync node (cheaper, removes one serialized launch per replay).

#define N 1024
#define NB 64
#define BT 128
#define NT2 (N / BT)                   // 8
#define NPAIR2 (NT2 * (NT2 + 1) / 2)   // 36

__global__ __launch_bounds__(512) void trace_pair_kernel(const float* __restrict__ x,
                                                         float* __restrict__ out) {
    __shared__ float bt[64][129];   // 32.25 KB; pad 129: transposed reads 2-way (free)
    __shared__ float red[16];

    const int blk = blockIdx.x;
    const int b   = blk / NPAIR2;
    int p = blk % NPAIR2;
    int bi = 0;
    while (p >= NT2 - bi) { p -= NT2 - bi; ++bi; }
    const int bj = bi + p;
    const bool diag = (bi == bj);

    const float* xb = x + (size_t)b * N * N;
    const int t  = threadIdx.x;
    const int g  = t & 31;    // float4 col within super-tile (0..31)
    const int rb = t >> 5;    // row base (0..15)

    const float* Arow0 = xb + (size_t)(BT * bi) * N + BT * bj + 4 * g;
    const float* Brow0 = xb + (size_t)(BT * bj) * N + BT * bi + 4 * g;

    // A super-tile: 8 rows/thread, 512B contiguous per wave-row.
    float4 av[8];
    #pragma unroll
    for (int rr = 0; rr < 8; ++rr) {
        av[rr] = *reinterpret_cast<const float4*>(Arow0 + (size_t)(rb + 16 * rr) * N);
    }

    // Phase-0 B rows (off-diag only): loader row lr covers c = 4*(lr>>1)+(lr&1).
    float4 bv[4];
    if (!diag) {
        #pragma unroll
        for (int q = 0; q < 4; ++q) {
            const int lr = rb + 16 * q;
            const int c  = 4 * (lr >> 1) + (lr & 1);
            bv[q] = *reinterpret_cast<const float4*>(Brow0 + (size_t)c * N);
        }
    }

    // Stage phase 0 (slot for row c is 2*(c>>2)+(c&1) == lr by construction).
    if (diag) {
        if (((rb >> 1) & 1) == 0) {
            #pragma unroll
            for (int rr = 0; rr < 8; ++rr) {
                const int r = rb + 16 * rr;
                const int slot = 2 * (r >> 2) + (r & 1);
                bt[slot][4 * g + 0] = av[rr].x;
                bt[slot][4 * g + 1] = av[rr].y;
                bt[slot][4 * g + 2] = av[rr].z;
                bt[slot][4 * g + 3] = av[rr].w;
            }
        }
    } else {
        #pragma unroll
        for (int q = 0; q < 4; ++q) {
            const int lr = rb + 16 * q;
            bt[lr][4 * g + 0] = bv[q].x;
            bt[lr][4 * g + 1] = bv[q].y;
            bt[lr][4 * g + 2] = bv[q].z;
            bt[lr][4 * g + 3] = bv[q].w;
        }
    }
    __syncthreads();

    // Prefetch phase-1 B rows (c = 4*(lr>>1)+2+(lr&1)) under phase-0 compute.
    if (!diag) {
        #pragma unroll
        for (int q = 0; q < 4; ++q) {
            const int lr = rb + 16 * q;
            const int c  = 4 * (lr >> 1) + 2 + (lr & 1);
            bv[q] = *reinterpret_cast<const float4*>(Brow0 + (size_t)c * N);
        }
    }

    float s  = 0.0f;
    float tr = 0.0f;

    // Compute phase 0: c = 4g+j, j in {0,1} -> av components x,y.
    #pragma unroll
    for (int rr = 0; rr < 8; ++rr) {
        const int r = rb + 16 * rr;
        s += av[rr].x * bt[2 * g + 0][r];
        s += av[rr].y * bt[2 * g + 1][r];
    }

    // Trace from registers (diag blocks own A==B; element (r,r) is held by
    // the thread with g == r>>2, rb == r&15; component = rb&3).
    if (diag) {
        const int cc = rb & 3;
        #pragma unroll
        for (int rr = 0; rr < 8; ++rr) {
            const int r = rb + 16 * rr;
            if ((r >> 2) == g) {
                tr += (cc == 0) ? av[rr].x : (cc == 1) ? av[rr].y
                    : (cc == 2) ? av[rr].z : av[rr].w;
            }
        }
    }

    __syncthreads();   // drain phase-0 reads before overwrite

    // Stage phase 1.
    if (diag) {
        if (((rb >> 1) & 1) == 1) {
            #pragma unroll
            for (int rr = 0; rr < 8; ++rr) {
                const int r = rb + 16 * rr;
                const int slot = 2 * (r >> 2) + (r & 1);
                bt[slot][4 * g + 0] = av[rr].x;
                bt[slot][4 * g + 1] = av[rr].y;
                bt[slot][4 * g + 2] = av[rr].z;
                bt[slot][4 * g + 3] = av[rr].w;
            }
        }
    } else {
        #pragma unroll
        for (int q = 0; q < 4; ++q) {
            const int lr = rb + 16 * q;
            bt[lr][4 * g + 0] = bv[q].x;
            bt[lr][4 * g + 1] = bv[q].y;
            bt[lr][4 * g + 2] = bv[q].z;
            bt[lr][4 * g + 3] = bv[q].w;
        }
    }
    __syncthreads();

    // Compute phase 1: c = 4g+2+j -> av components z,w. Same LDS slots.
    #pragma unroll
    for (int rr = 0; rr < 8; ++rr) {
        const int r = rb + 16 * rr;
        s += av[rr].z * bt[2 * g + 0][r];
        s += av[rr].w * bt[2 * g + 1][r];
    }

    if (!diag) s *= 2.0f;   // (BI,BJ) and (BJ,BI) contribute equally

    // Block reduction: wave64 shuffle, then cross-wave via LDS (8 waves).
    #pragma unroll
    for (int off = 32; off > 0; off >>= 1) {
        s  += __shfl_down(s,  off, 64);
        tr += __shfl_down(tr, off, 64);
    }
    const int wave = t >> 6;
    const int lane = t & 63;
    if (lane == 0) { red[wave] = s; red[8 + wave] = tr; }
    __syncthreads();
    if (t == 0) {
        float st = 0.0f, trt = 0.0f;
        #pragma unroll
        for (int w = 0; w < 8; ++w) { st += red[w]; trt += red[8 + w]; }
        atomicAdd(out + NB + b, st);
        if (diag) atomicAdd(out + b, trt);
    }
}

extern "C" void kernel_launch(void* const* d_in, const int* in_sizes, int n_in,
                              void* d_out, int out_size, void* d_ws, size_t ws_size,
                              hipStream_t stream) {
    (void)in_sizes; (void)n_in; (void)d_ws; (void)ws_size; (void)out_size;
    const float* x = (const float*)d_in[0];
    float* out = (float*)d_out;

    hipMemsetAsync(out, 0, 2 * NB * sizeof(float), stream);   // 0x00 == 0.0f
    trace_pair_kernel<<<NB * NPAIR2, 512, 0, stream>>>(x, out);
}

// Round 6
// 50.152 us; speedup vs baseline: 1.0982x; 1.0160x over previous
//
#include <hip/hip_runtime.h>

// x (64, 1024, 1024) fp32.
// out[0..63]   = trace(x[b])        = sum_i x[b,i,i]
// out[64..127] = trace(x[b] @ x[b]) = sum_{i,j} x[b,i,j]*x[b,j,i]
//
// R3: 128x128 super-tile pairs; every global read is a 512B contiguous
// wave-segment; B staged in two 32KB LDS phases (interleaved row-pairs);
// A held in 32 VGPRs; HBM traffic exactly 256 MiB. 49.6 us.
// R4: non-temporal loads REGRESSED (55.1): input fits L3; nt bypasses it.
// R5: memset node instead of zero-kernel: slightly worse (51.0). Reverted.
// R6: zero-kernel restored + ALL B rows (both phases) loaded up front in
// issue order bv0 -> av -> bv1, so each block has exactly ONE HBM
// round-trip (stage-0 at vmcnt(12), compute-0 at vmcnt(4), stage-1 at 0).

#define N 1024
#define NB 64
#define BT 128
#define NT2 (N / BT)                   // 8
#define NPAIR2 (NT2 * (NT2 + 1) / 2)   // 36

__global__ void zero_out_kernel(float* out) {
    int t = threadIdx.x;
    if (t < 2 * NB) out[t] = 0.0f;
}

__global__ __launch_bounds__(512) void trace_pair_kernel(const float* __restrict__ x,
                                                         float* __restrict__ out) {
    __shared__ float bt[64][129];   // 32.25 KB; pad 129: transposed reads 2-way (free)
    __shared__ float red[16];

    const int blk = blockIdx.x;
    const int b   = blk / NPAIR2;
    int p = blk % NPAIR2;
    int bi = 0;
    while (p >= NT2 - bi) { p -= NT2 - bi; ++bi; }
    const int bj = bi + p;
    const bool diag = (bi == bj);

    const float* xb = x + (size_t)b * N * N;
    const int t  = threadIdx.x;
    const int g  = t & 31;    // float4 col within super-tile (0..31)
    const int rb = t >> 5;    // row base (0..15)

    const float* Arow0 = xb + (size_t)(BT * bi) * N + BT * bj + 4 * g;
    const float* Brow0 = xb + (size_t)(BT * bj) * N + BT * bi + 4 * g;

    // Off-diag: issue phase-0 B rows FIRST (stage-0 can start while the
    // rest are still in flight), then A, then phase-1 B rows.
    float4 bv0[4], bv1[4];
    if (!diag) {
        #pragma unroll
        for (int q = 0; q < 4; ++q) {
            const int lr = rb + 16 * q;
            const int c  = 4 * (lr >> 1) + (lr & 1);
            bv0[q] = *reinterpret_cast<const float4*>(Brow0 + (size_t)c * N);
        }
    }

    // A super-tile: 8 rows/thread, 512B contiguous per wave-row.
    float4 av[8];
    #pragma unroll
    for (int rr = 0; rr < 8; ++rr) {
        av[rr] = *reinterpret_cast<const float4*>(Arow0 + (size_t)(rb + 16 * rr) * N);
    }

    if (!diag) {
        #pragma unroll
        for (int q = 0; q < 4; ++q) {
            const int lr = rb + 16 * q;
            const int c  = 4 * (lr >> 1) + 2 + (lr & 1);
            bv1[q] = *reinterpret_cast<const float4*>(Brow0 + (size_t)c * N);
        }
    }

    // Stage phase 0 (slot for row c is 2*(c>>2)+(c&1) == lr by construction).
    if (diag) {
        if (((rb >> 1) & 1) == 0) {
            #pragma unroll
            for (int rr = 0; rr < 8; ++rr) {
                const int r = rb + 16 * rr;
                const int slot = 2 * (r >> 2) + (r & 1);
                bt[slot][4 * g + 0] = av[rr].x;
                bt[slot][4 * g + 1] = av[rr].y;
                bt[slot][4 * g + 2] = av[rr].z;
                bt[slot][4 * g + 3] = av[rr].w;
            }
        }
    } else {
        #pragma unroll
        for (int q = 0; q < 4; ++q) {
            const int lr = rb + 16 * q;
            bt[lr][4 * g + 0] = bv0[q].x;
            bt[lr][4 * g + 1] = bv0[q].y;
            bt[lr][4 * g + 2] = bv0[q].z;
            bt[lr][4 * g + 3] = bv0[q].w;
        }
    }
    __syncthreads();

    float s  = 0.0f;
    float tr = 0.0f;

    // Compute phase 0: c = 4g+j, j in {0,1} -> av components x,y.
    #pragma unroll
    for (int rr = 0; rr < 8; ++rr) {
        const int r = rb + 16 * rr;
        s += av[rr].x * bt[2 * g + 0][r];
        s += av[rr].y * bt[2 * g + 1][r];
    }

    // Trace from registers (diag blocks own A==B; element (r,r) is held by
    // the thread with g == r>>2, rb == r&15; component = rb&3).
    if (diag) {
        const int cc = rb & 3;
        #pragma unroll
        for (int rr = 0; rr < 8; ++rr) {
            const int r = rb + 16 * rr;
            if ((r >> 2) == g) {
                tr += (cc == 0) ? av[rr].x : (cc == 1) ? av[rr].y
                    : (cc == 2) ? av[rr].z : av[rr].w;
            }
        }
    }

    __syncthreads();   // drain phase-0 reads before overwrite

    // Stage phase 1.
    if (diag) {
        if (((rb >> 1) & 1) == 1) {
            #pragma unroll
            for (int rr = 0; rr < 8; ++rr) {
                const int r = rb + 16 * rr;
                const int slot = 2 * (r >> 2) + (r & 1);
                bt[slot][4 * g + 0] = av[rr].x;
                bt[slot][4 * g + 1] = av[rr].y;
                bt[slot][4 * g + 2] = av[rr].z;
                bt[slot][4 * g + 3] = av[rr].w;
            }
        }
    } else {
        #pragma unroll
        for (int q = 0; q < 4; ++q) {
            const int lr = rb + 16 * q;
            bt[lr][4 * g + 0] = bv1[q].x;
            bt[lr][4 * g + 1] = bv1[q].y;
            bt[lr][4 * g + 2] = bv1[q].z;
            bt[lr][4 * g + 3] = bv1[q].w;
        }
    }
    __syncthreads();

    // Compute phase 1: c = 4g+2+j -> av components z,w. Same LDS slots.
    #pragma unroll
    for (int rr = 0; rr < 8; ++rr) {
        const int r = rb + 16 * rr;
        s += av[rr].z * bt[2 * g + 0][r];
        s += av[rr].w * bt[2 * g + 1][r];
    }

    if (!diag) s *= 2.0f;   // (BI,BJ) and (BJ,BI) contribute equally

    // Block reduction: wave64 shuffle, then cross-wave via LDS (8 waves).
    #pragma unroll
    for (int off = 32; off > 0; off >>= 1) {
        s  += __shfl_down(s,  off, 64);
        tr += __shfl_down(tr, off, 64);
    }
    const int wave = t >> 6;
    const int lane = t & 63;
    if (lane == 0) { red[wave] = s; red[8 + wave] = tr; }
    __syncthreads();
    if (t == 0) {
        float st = 0.0f, trt = 0.0f;
        #pragma unroll
        for (int w = 0; w < 8; ++w) { st += red[w]; trt += red[8 + w]; }
        atomicAdd(out + NB + b, st);
        if (diag) atomicAdd(out + b, trt);
    }
}

extern "C" void kernel_launch(void* const* d_in, const int* in_sizes, int n_in,
                              void* d_out, int out_size, void* d_ws, size_t ws_size,
                              hipStream_t stream) {
    (void)in_sizes; (void)n_in; (void)d_ws; (void)ws_size; (void)out_size;
    const float* x = (const float*)d_in[0];
    float* out = (float*)d_out;

    zero_out_kernel<<<1, 128, 0, stream>>>(out);
    trace_pair_kernel<<<NB * NPAIR2, 512, 0, stream>>>(x, out);
}